// Round 1
// baseline (358.087 us; speedup 1.0000x reference)
//
#include <hip/hip_runtime.h>
#include <math.h>

// NetVLAD fp32, MI355X. Shapes fixed by the reference.
#define N_B   32
#define C_DIM 512
#define K_DIM 64
#define HW    1200
#define PTILE 32
#define NPT   ((HW + PTILE - 1) / PTILE)   // 38 pixel tiles
#define ASLOT 40                           // padded slots for asum partials

// ---------------------------------------------------------------------------
// Kernel 1: per-pixel channel L2-norm + logits (W @ X) + softmax over K.
// Grid: N_B * NPT blocks, 256 threads. Each block: 32 pixels, all 64 k.
// Writes: a[n][k][h], invnorm[n][h], asum_part[n][k][tile].
// Normalization folded in post-hoc: logits = (W·x) * invnorm (linear).
// ---------------------------------------------------------------------------
__global__ __launch_bounds__(256) void k1_logits_softmax(
    const float* __restrict__ x, const float* __restrict__ w,
    float* __restrict__ a_out, float* __restrict__ invnorm_out,
    float* __restrict__ asum_part)
{
  __shared__ float xs[64][32];   // [c-chunk][pixel] bank = pp -> conflict-free
  __shared__ float ws[64][64];   // [k][c-chunk]     broadcast reads
  __shared__ float red[8][32];

  const int tid = threadIdx.x;
  const int pp  = tid & 31;      // pixel within tile
  const int q   = tid >> 5;      // 0..7, owns k = q*8+j
  const int n    = blockIdx.x / NPT;
  const int tile = blockIdx.x % NPT;
  const int p0   = tile * PTILE;
  const int p    = p0 + pp;
  const bool pvalid = p < HW;

  const float* xb = x + (size_t)n * C_DIM * HW;

  float acc[8];
#pragma unroll
  for (int j = 0; j < 8; ++j) acc[j] = 0.f;
  float ssq = 0.f;

  for (int c0 = 0; c0 < C_DIM; c0 += 64) {
    // stage x chunk [64 c][32 p]; thread always loads pixel pp (coalesced in h)
#pragma unroll
    for (int i = 0; i < 8; ++i) {
      int cc = i * 8 + q;
      float v = pvalid ? xb[(size_t)(c0 + cc) * HW + p] : 0.f;
      ssq += v * v;
      xs[cc][pp] = v;
    }
    // stage w chunk [64 k][64 c] (contiguous in c -> coalesced)
#pragma unroll
    for (int i = 0; i < 16; ++i) {
      int idx = i * 256 + tid;
      int k = idx >> 6, cc = idx & 63;
      ws[k][cc] = w[(size_t)k * C_DIM + c0 + cc];
    }
    __syncthreads();
#pragma unroll 4
    for (int cc = 0; cc < 64; ++cc) {
      float xv = xs[cc][pp];
#pragma unroll
      for (int j = 0; j < 8; ++j)
        acc[j] = fmaf(ws[q * 8 + j][cc], xv, acc[j]);
    }
    __syncthreads();
  }

  // per-pixel sumsq reduce across the 8 q-groups
  red[q][pp] = ssq;
  __syncthreads();
  float s = 0.f;
#pragma unroll
  for (int j = 0; j < 8; ++j) s += red[j][pp];
  float inv = 1.f / fmaxf(sqrtf(s), 1e-12f);   // torch F.normalize eps semantics
  if (q == 0 && pvalid) invnorm_out[n * HW + p] = inv;

  // finalize logits, softmax over 64 k (8 per thread x 8 threads per pixel)
  float lmax = -INFINITY;
#pragma unroll
  for (int j = 0; j < 8; ++j) { acc[j] *= inv; lmax = fmaxf(lmax, acc[j]); }
  __syncthreads();
  red[q][pp] = lmax;
  __syncthreads();
  float m = red[0][pp];
#pragma unroll
  for (int j = 1; j < 8; ++j) m = fmaxf(m, red[j][pp]);
  float lsum = 0.f;
#pragma unroll
  for (int j = 0; j < 8; ++j) { acc[j] = __expf(acc[j] - m); lsum += acc[j]; }
  __syncthreads();
  red[q][pp] = lsum;
  __syncthreads();
  s = 0.f;
#pragma unroll
  for (int j = 0; j < 8; ++j) s += red[j][pp];
  float sinv = 1.f / s;

#pragma unroll
  for (int j = 0; j < 8; ++j) {
    int k = q * 8 + j;
    float av = acc[j] * sinv;
    if (pvalid) a_out[((size_t)n * K_DIM + k) * HW + p] = av;
    float t = pvalid ? av : 0.f;
    // sum over the 32 pixels of this tile (stays within half-wave)
#pragma unroll
    for (int off = 16; off > 0; off >>= 1) t += __shfl_xor(t, off);
    if (pp == 0) asum_part[((size_t)n * K_DIM + k) * ASLOT + tile] = t;
  }
}

// ---------------------------------------------------------------------------
// Kernel 2: vlad_raw[n][k][c] = sum_h a[n][k][h] * x[n][c][h] * invnorm[n][h]
// Batched GEMM M=64, N=512(c), K=1200(h). Grid: N_B * 8 c-tiles * 2 h-halves
// = 512 blocks, 256 threads, 4x4 register tile/thread, [64k][64c] block tile.
// Writes partials part[half][n][k][c].
// ---------------------------------------------------------------------------
__global__ __launch_bounds__(256) void k2_vlad_gemm(
    const float* __restrict__ x, const float* __restrict__ a_in,
    const float* __restrict__ invnorm, float* __restrict__ part)
{
  __shared__ float as_t[32 * 68];   // [hh][k], stride 68 keeps f4 align + banks
  __shared__ float xs_t[32 * 68];   // [hh][c]

  const int tid  = threadIdx.x;
  const int b    = blockIdx.x;
  const int n    = b >> 4;
  const int r    = b & 15;
  const int c0   = (r >> 1) * 64;
  const int hbase = (r & 1) * 600;

  const int tk = tid >> 4;          // 0..15 -> k0 = tk*4
  const int tc = tid & 15;          // 0..15 -> c  = c0 + tc*4

  const float* ab  = a_in   + (size_t)n * K_DIM * HW;
  const float* xb  = x      + (size_t)n * C_DIM * HW;
  const float* inb = invnorm + (size_t)n * HW;

  float acc[4][4];
#pragma unroll
  for (int i = 0; i < 4; ++i)
#pragma unroll
    for (int j = 0; j < 4; ++j) acc[i][j] = 0.f;

  for (int ch = 0; ch < 600; ch += 32) {
    int hvalid = 600 - ch; if (hvalid > 32) hvalid = 32;
#pragma unroll
    for (int i = 0; i < 8; ++i) {
      int idx = i * 256 + tid;
      int kk = idx >> 5, hh = idx & 31;        // kk doubles as c index below
      int h  = hbase + ch + hh;
      float av = (hh < hvalid) ? ab[(size_t)kk * HW + h] : 0.f;
      as_t[hh * 68 + kk] = av;
      float xv = (hh < hvalid) ? xb[(size_t)(c0 + kk) * HW + h] * inb[h] : 0.f;
      xs_t[hh * 68 + kk] = xv;
    }
    __syncthreads();
#pragma unroll
    for (int hh = 0; hh < 32; ++hh) {
      float4 av = *(const float4*)&as_t[hh * 68 + tk * 4];
      float4 xv = *(const float4*)&xs_t[hh * 68 + tc * 4];
      acc[0][0] = fmaf(av.x, xv.x, acc[0][0]);
      acc[0][1] = fmaf(av.x, xv.y, acc[0][1]);
      acc[0][2] = fmaf(av.x, xv.z, acc[0][2]);
      acc[0][3] = fmaf(av.x, xv.w, acc[0][3]);
      acc[1][0] = fmaf(av.y, xv.x, acc[1][0]);
      acc[1][1] = fmaf(av.y, xv.y, acc[1][1]);
      acc[1][2] = fmaf(av.y, xv.z, acc[1][2]);
      acc[1][3] = fmaf(av.y, xv.w, acc[1][3]);
      acc[2][0] = fmaf(av.z, xv.x, acc[2][0]);
      acc[2][1] = fmaf(av.z, xv.y, acc[2][1]);
      acc[2][2] = fmaf(av.z, xv.z, acc[2][2]);
      acc[2][3] = fmaf(av.z, xv.w, acc[2][3]);
      acc[3][0] = fmaf(av.w, xv.x, acc[3][0]);
      acc[3][1] = fmaf(av.w, xv.y, acc[3][1]);
      acc[3][2] = fmaf(av.w, xv.z, acc[3][2]);
      acc[3][3] = fmaf(av.w, xv.w, acc[3][3]);
    }
    __syncthreads();
  }

  float* pb = part + (((size_t)(r & 1) * N_B + n) * K_DIM) * C_DIM;
#pragma unroll
  for (int jk = 0; jk < 4; ++jk) {
    float4 v = make_float4(acc[jk][0], acc[jk][1], acc[jk][2], acc[jk][3]);
    *(float4*)&pb[(size_t)(tk * 4 + jk) * C_DIM + c0 + tc * 4] = v;
  }
}

// ---------------------------------------------------------------------------
// Kernel 3a: v = part0 + part1 - asum*centroid; intra-normalize over C.
// Grid: N_B*K_DIM = 2048 blocks, 128 threads (4 c each). Writes out + rowsum.
// ---------------------------------------------------------------------------
__global__ __launch_bounds__(128) void k3a_intranorm(
    const float* __restrict__ part, const float* __restrict__ cent,
    const float* __restrict__ asum_part, float* __restrict__ out,
    float* __restrict__ rowsum)
{
  const int nk = blockIdx.x;
  const int n = nk >> 6, k = nk & 63;
  const int tid = threadIdx.x;

  __shared__ float sasum;
  __shared__ float wss[2];

  float t = (tid < NPT) ? asum_part[(size_t)nk * ASLOT + tid] : 0.f;
  if (tid < 64) {
#pragma unroll
    for (int off = 32; off > 0; off >>= 1) t += __shfl_xor(t, off);
    if (tid == 0) sasum = t;
  }
  __syncthreads();
  const float asum = sasum;

  const float* p0 = part + ((size_t)n * K_DIM + k) * C_DIM;
  const float* p1 = part + ((size_t)(N_B + n) * K_DIM + k) * C_DIM;
  const float* cb = cent + (size_t)k * C_DIM;

  float4 a4 = *(const float4*)&p0[tid * 4];
  float4 b4 = *(const float4*)&p1[tid * 4];
  float4 c4 = *(const float4*)&cb[tid * 4];
  float4 v;
  v.x = a4.x + b4.x - asum * c4.x;
  v.y = a4.y + b4.y - asum * c4.y;
  v.z = a4.z + b4.z - asum * c4.z;
  v.w = a4.w + b4.w - asum * c4.w;

  float ss = v.x * v.x + v.y * v.y + v.z * v.z + v.w * v.w;
#pragma unroll
  for (int off = 32; off > 0; off >>= 1) ss += __shfl_xor(ss, off);
  if ((tid & 63) == 0) wss[tid >> 6] = ss;
  __syncthreads();
  float tot = wss[0] + wss[1];
  float inv = 1.f / fmaxf(sqrtf(tot), 1e-12f);

  float4 o = make_float4(v.x * inv, v.y * inv, v.z * inv, v.w * inv);
  *(float4*)&out[(size_t)n * (K_DIM * C_DIM) + k * C_DIM + tid * 4] = o;
  if (tid == 0) rowsum[nk] = tot * inv * inv;   // ==1 unless degenerate row
}

// ---------------------------------------------------------------------------
// Kernel 3b: global L2 over flattened [K*C] per n; scale in place.
// Grid: N_B*8 = 256 blocks, 256 threads, 4096 elems/block.
// ---------------------------------------------------------------------------
__global__ __launch_bounds__(256) void k3b_globalnorm(
    const float* __restrict__ rowsum, float* __restrict__ out)
{
  const int b = blockIdx.x;
  const int n = b >> 3, seg = b & 7;
  const int tid = threadIdx.x;

  __shared__ float sg;
  float t = (tid < 64) ? rowsum[n * 64 + tid] : 0.f;
  if (tid < 64) {
#pragma unroll
    for (int off = 32; off > 0; off >>= 1) t += __shfl_xor(t, off);
    if (tid == 0) sg = t;
  }
  __syncthreads();
  float ginv = 1.f / fmaxf(sqrtf(sg), 1e-12f);

  float* ob = out + (size_t)n * (K_DIM * C_DIM) + seg * 4096;
#pragma unroll
  for (int i = 0; i < 4; ++i) {
    float4 v = *(float4*)&ob[(i * 256 + tid) * 4];
    v.x *= ginv; v.y *= ginv; v.z *= ginv; v.w *= ginv;
    *(float4*)&ob[(i * 256 + tid) * 4] = v;
  }
}

// ---------------------------------------------------------------------------
extern "C" void kernel_launch(void* const* d_in, const int* in_sizes, int n_in,
                              void* d_out, int out_size, void* d_ws, size_t ws_size,
                              hipStream_t stream) {
  (void)in_sizes; (void)n_in; (void)out_size; (void)ws_size;
  const float* x    = (const float*)d_in[0];   // [32,512,30,40]
  const float* w    = (const float*)d_in[1];   // [64,512]
  const float* cent = (const float*)d_in[2];   // [64,512]
  float* out = (float*)d_out;

  // workspace layout (bytes)
  char* ws = (char*)d_ws;
  float* a_buf    = (float*)(ws);                                  // 9,830,400
  float* invnorm  = (float*)(ws + 9830400);                        //   153,600
  float* asum_p   = (float*)(ws + 9984000);                        //   327,680
  float* part     = (float*)(ws + 10311680);                       //16,777,216
  float* rowsum   = (float*)(ws + 27088896);                       //     8,192

  k1_logits_softmax<<<N_B * NPT, 256, 0, stream>>>(x, w, a_buf, invnorm, asum_p);
  k2_vlad_gemm<<<N_B * 16, 256, 0, stream>>>(x, a_buf, invnorm, part);
  k3a_intranorm<<<N_B * K_DIM, 128, 0, stream>>>(part, cent, asum_p, out, rowsum);
  k3b_globalnorm<<<N_B * 8, 256, 0, stream>>>(rowsum, out);
}

// Round 2
// 305.467 us; speedup vs baseline: 1.1723x; 1.1723x over previous
//
#include <hip/hip_runtime.h>
#include <math.h>

// NetVLAD fp32, MI355X. Shapes fixed by the reference.
#define N_B   32
#define C_DIM 512
#define K_DIM 64
#define HW    1200
#define PTILE 32
#define NPT   ((HW + PTILE - 1) / PTILE)   // 38 pixel tiles
#define ASLOT 40                           // padded slots for asum partials

// ---------------------------------------------------------------------------
// Kernel 1: logits GEMM (64k x 32p, K=512c) + fused channel-sumsq + softmax.
// Grid: N_B*NPT = 1216 blocks, 128 threads. Thread tile 4k x 4p, float4 LDS
// fragment reads (2 ds_read_b128 per 16 FMA). invnorm folded post-GEMM
// (logits = (W.x)*inv since the channel norm is a per-pixel scalar).
// ---------------------------------------------------------------------------
__global__ __launch_bounds__(128) void k1_logits_softmax(
    const float* __restrict__ x, const float* __restrict__ w,
    float* __restrict__ a_out, float* __restrict__ invnorm_out,
    float* __restrict__ asum_part)
{
  __shared__ float wT[32 * 68];     // [cc][k]  (transposed W chunk, pad 68)
  __shared__ float xs[32 * 36];     // [cc][p]  (X chunk, pad 36)
  __shared__ float red16[16 * 32];  // [tk][p] softmax partials
  __shared__ float sred[4 * 32];    // sumsq partials
  __shared__ float pinv[32], pmax[32], psum[32];

  const int tid = threadIdx.x;
  const int tk = tid >> 3;          // 0..15 -> k0 = tk*4
  const int tp = tid & 7;           // 0..7  -> p  = tp*4..+3
  const int n    = blockIdx.x / NPT;
  const int tile = blockIdx.x % NPT;
  const int p0   = tile * PTILE;

  const int sp = tid & 31;          // staging pixel
  const int sq = tid >> 5;          // 0..3
  const bool spv = (p0 + sp) < HW;

  const float* xb = x + (size_t)n * C_DIM * HW;

  float acc[4][4];
#pragma unroll
  for (int i = 0; i < 4; ++i)
#pragma unroll
    for (int j = 0; j < 4; ++j) acc[i][j] = 0.f;
  float ssq = 0.f;

  for (int c0 = 0; c0 < C_DIM; c0 += 32) {
    // stage W chunk transposed: [32cc][64k]; coalesced over c
#pragma unroll
    for (int i = 0; i < 16; ++i) {
      int idx = i * 128 + tid;
      int cc = idx & 31, k = idx >> 5;
      wT[cc * 68 + k] = w[(size_t)k * C_DIM + c0 + cc];
    }
    // stage X chunk [32cc][32p]; coalesced over p; fuse sumsq
#pragma unroll
    for (int i = 0; i < 8; ++i) {
      int cc = i * 4 + sq;
      float v = spv ? xb[(size_t)(c0 + cc) * HW + p0 + sp] : 0.f;
      ssq += v * v;
      xs[cc * 36 + sp] = v;
    }
    __syncthreads();
#pragma unroll 4
    for (int cc = 0; cc < 32; ++cc) {
      float4 wv = *(const float4*)&wT[cc * 68 + tk * 4];
      float4 xv = *(const float4*)&xs[cc * 36 + tp * 4];
      acc[0][0] = fmaf(wv.x, xv.x, acc[0][0]);
      acc[0][1] = fmaf(wv.x, xv.y, acc[0][1]);
      acc[0][2] = fmaf(wv.x, xv.z, acc[0][2]);
      acc[0][3] = fmaf(wv.x, xv.w, acc[0][3]);
      acc[1][0] = fmaf(wv.y, xv.x, acc[1][0]);
      acc[1][1] = fmaf(wv.y, xv.y, acc[1][1]);
      acc[1][2] = fmaf(wv.y, xv.z, acc[1][2]);
      acc[1][3] = fmaf(wv.y, xv.w, acc[1][3]);
      acc[2][0] = fmaf(wv.z, xv.x, acc[2][0]);
      acc[2][1] = fmaf(wv.z, xv.y, acc[2][1]);
      acc[2][2] = fmaf(wv.z, xv.z, acc[2][2]);
      acc[2][3] = fmaf(wv.z, xv.w, acc[2][3]);
      acc[3][0] = fmaf(wv.w, xv.x, acc[3][0]);
      acc[3][1] = fmaf(wv.w, xv.y, acc[3][1]);
      acc[3][2] = fmaf(wv.w, xv.z, acc[3][2]);
      acc[3][3] = fmaf(wv.w, xv.w, acc[3][3]);
    }
    __syncthreads();
  }

  // per-pixel inv norm: reduce ssq across the 4 staging quarters
  sred[sq * 32 + sp] = ssq;
  __syncthreads();
  if (tid < 32) {
    float s = sred[tid] + sred[32 + tid] + sred[64 + tid] + sred[96 + tid];
    pinv[tid] = 1.f / fmaxf(sqrtf(s), 1e-12f);   // torch F.normalize eps
  }
  __syncthreads();

  // scale logits by per-pixel inv (must precede softmax: softmax(c*l) != softmax(l))
  float iv[4];
#pragma unroll
  for (int j = 0; j < 4; ++j) iv[j] = pinv[tp * 4 + j];
#pragma unroll
  for (int i = 0; i < 4; ++i)
#pragma unroll
    for (int j = 0; j < 4; ++j) acc[i][j] *= iv[j];

  if (tid < 32 && spv) invnorm_out[n * HW + p0 + tid] = pinv[tid];

  // softmax over 64 k per pixel column: max
#pragma unroll
  for (int j = 0; j < 4; ++j) {
    float m = fmaxf(fmaxf(acc[0][j], acc[1][j]), fmaxf(acc[2][j], acc[3][j]));
    red16[tk * 32 + tp * 4 + j] = m;
  }
  __syncthreads();
  if (tid < 32) {
    float m = red16[tid];
#pragma unroll
    for (int t = 1; t < 16; ++t) m = fmaxf(m, red16[t * 32 + tid]);
    pmax[tid] = m;
  }
  __syncthreads();
  float mj[4];
#pragma unroll
  for (int j = 0; j < 4; ++j) mj[j] = pmax[tp * 4 + j];

  // exp + sum
#pragma unroll
  for (int i = 0; i < 4; ++i)
#pragma unroll
    for (int j = 0; j < 4; ++j) acc[i][j] = __expf(acc[i][j] - mj[j]);
#pragma unroll
  for (int j = 0; j < 4; ++j) {
    float s = acc[0][j] + acc[1][j] + acc[2][j] + acc[3][j];
    red16[tk * 32 + tp * 4 + j] = s;
  }
  __syncthreads();
  if (tid < 32) {
    float s = 0.f;
#pragma unroll
    for (int t = 0; t < 16; ++t) s += red16[t * 32 + tid];
    psum[tid] = 1.f / s;
  }
  __syncthreads();
  float rs[4];
#pragma unroll
  for (int j = 0; j < 4; ++j) rs[j] = psum[tp * 4 + j];

  const bool colv = (p0 + tp * 4) < HW;   // valid counts are multiples of 4
#pragma unroll
  for (int i = 0; i < 4; ++i) {
    int k = tk * 4 + i;
    float4 av = make_float4(acc[i][0] * rs[0], acc[i][1] * rs[1],
                            acc[i][2] * rs[2], acc[i][3] * rs[3]);
    if (colv)
      *(float4*)&a_out[((size_t)n * K_DIM + k) * HW + p0 + tp * 4] = av;
    // tile-local sum over pixels for asum
    float t = colv ? (av.x + av.y + av.z + av.w) : 0.f;
#pragma unroll
    for (int off = 4; off > 0; off >>= 1) t += __shfl_xor(t, off);  // 8-lane tp group
    if (tp == 0) asum_part[((size_t)n * K_DIM + k) * ASLOT + tile] = t;
  }
}

// ---------------------------------------------------------------------------
// Kernel 2: vlad_raw[n][k][c] = sum_h a[n][k][h] * x[n][c][h] * invnorm[n][h]
// Batched GEMM M=64(k), N=512(c), K=1200(h). Tile 64k x 32c, 128 threads,
// 4x4 register tile. Grid: 32n * 16ctile * 2half = 1024 blocks.
// ---------------------------------------------------------------------------
__global__ __launch_bounds__(128) void k2_vlad_gemm(
    const float* __restrict__ x, const float* __restrict__ a_in,
    const float* __restrict__ invnorm, float* __restrict__ part)
{
  __shared__ float as_t[32 * 68];   // [hh][k]
  __shared__ float xs_t[32 * 36];   // [hh][c]

  const int tid  = threadIdx.x;
  const int b    = blockIdx.x;
  const int n    = b >> 5;
  const int r    = b & 31;
  const int c0   = (r >> 1) * 32;
  const int hbase = (r & 1) * 600;

  const int tk = tid >> 3;          // 0..15 -> k0 = tk*4
  const int tc = tid & 7;           // 0..7  -> c  = c0 + tc*4

  const float* ab  = a_in    + (size_t)n * K_DIM * HW;
  const float* xb  = x       + (size_t)n * C_DIM * HW;
  const float* inb = invnorm + (size_t)n * HW;

  float acc[4][4];
#pragma unroll
  for (int i = 0; i < 4; ++i)
#pragma unroll
    for (int j = 0; j < 4; ++j) acc[i][j] = 0.f;

  for (int ch = 0; ch < 600; ch += 32) {
    int hvalid = 600 - ch; if (hvalid > 32) hvalid = 32;
    // stage a tile [64k][32h] transposed -> [hh][k]
#pragma unroll
    for (int i = 0; i < 16; ++i) {
      int idx = i * 128 + tid;
      int hh = idx & 31, k = idx >> 5;
      int h  = hbase + ch + hh;
      as_t[hh * 68 + k] = (hh < hvalid) ? ab[(size_t)k * HW + h] : 0.f;
    }
    // stage x tile [32c][32h] transposed -> [hh][c], fused invnorm
#pragma unroll
    for (int i = 0; i < 8; ++i) {
      int idx = i * 128 + tid;
      int hh = idx & 31, cc = idx >> 5;
      int h  = hbase + ch + hh;
      xs_t[hh * 36 + cc] = (hh < hvalid)
          ? xb[(size_t)(c0 + cc) * HW + h] * inb[h] : 0.f;
    }
    __syncthreads();
#pragma unroll 4
    for (int hh = 0; hh < 32; ++hh) {
      float4 av = *(const float4*)&as_t[hh * 68 + tk * 4];
      float4 xv = *(const float4*)&xs_t[hh * 36 + tc * 4];
      acc[0][0] = fmaf(av.x, xv.x, acc[0][0]);
      acc[0][1] = fmaf(av.x, xv.y, acc[0][1]);
      acc[0][2] = fmaf(av.x, xv.z, acc[0][2]);
      acc[0][3] = fmaf(av.x, xv.w, acc[0][3]);
      acc[1][0] = fmaf(av.y, xv.x, acc[1][0]);
      acc[1][1] = fmaf(av.y, xv.y, acc[1][1]);
      acc[1][2] = fmaf(av.y, xv.z, acc[1][2]);
      acc[1][3] = fmaf(av.y, xv.w, acc[1][3]);
      acc[2][0] = fmaf(av.z, xv.x, acc[2][0]);
      acc[2][1] = fmaf(av.z, xv.y, acc[2][1]);
      acc[2][2] = fmaf(av.z, xv.z, acc[2][2]);
      acc[2][3] = fmaf(av.z, xv.w, acc[2][3]);
      acc[3][0] = fmaf(av.w, xv.x, acc[3][0]);
      acc[3][1] = fmaf(av.w, xv.y, acc[3][1]);
      acc[3][2] = fmaf(av.w, xv.z, acc[3][2]);
      acc[3][3] = fmaf(av.w, xv.w, acc[3][3]);
    }
    __syncthreads();
  }

  float* pb = part + (((size_t)(r & 1) * N_B + n) * K_DIM) * C_DIM;
#pragma unroll
  for (int jk = 0; jk < 4; ++jk) {
    float4 v = make_float4(acc[jk][0], acc[jk][1], acc[jk][2], acc[jk][3]);
    *(float4*)&pb[(size_t)(tk * 4 + jk) * C_DIM + c0 + tc * 4] = v;
  }
}

// ---------------------------------------------------------------------------
// Kernel 3a: v = part0 + part1 - asum*centroid; intra-normalize over C.
// Grid: N_B*K_DIM = 2048 blocks, 128 threads (4 c each). Writes out + rowsum.
// ---------------------------------------------------------------------------
__global__ __launch_bounds__(128) void k3a_intranorm(
    const float* __restrict__ part, const float* __restrict__ cent,
    const float* __restrict__ asum_part, float* __restrict__ out,
    float* __restrict__ rowsum)
{
  const int nk = blockIdx.x;
  const int n = nk >> 6, k = nk & 63;
  const int tid = threadIdx.x;

  __shared__ float sasum;
  __shared__ float wss[2];

  float t = (tid < NPT) ? asum_part[(size_t)nk * ASLOT + tid] : 0.f;
  if (tid < 64) {
#pragma unroll
    for (int off = 32; off > 0; off >>= 1) t += __shfl_xor(t, off);
    if (tid == 0) sasum = t;
  }
  __syncthreads();
  const float asum = sasum;

  const float* p0 = part + ((size_t)n * K_DIM + k) * C_DIM;
  const float* p1 = part + ((size_t)(N_B + n) * K_DIM + k) * C_DIM;
  const float* cb = cent + (size_t)k * C_DIM;

  float4 a4 = *(const float4*)&p0[tid * 4];
  float4 b4 = *(const float4*)&p1[tid * 4];
  float4 c4 = *(const float4*)&cb[tid * 4];
  float4 v;
  v.x = a4.x + b4.x - asum * c4.x;
  v.y = a4.y + b4.y - asum * c4.y;
  v.z = a4.z + b4.z - asum * c4.z;
  v.w = a4.w + b4.w - asum * c4.w;

  float ss = v.x * v.x + v.y * v.y + v.z * v.z + v.w * v.w;
#pragma unroll
  for (int off = 32; off > 0; off >>= 1) ss += __shfl_xor(ss, off);
  if ((tid & 63) == 0) wss[tid >> 6] = ss;
  __syncthreads();
  float tot = wss[0] + wss[1];
  float inv = 1.f / fmaxf(sqrtf(tot), 1e-12f);

  float4 o = make_float4(v.x * inv, v.y * inv, v.z * inv, v.w * inv);
  *(float4*)&out[(size_t)n * (K_DIM * C_DIM) + k * C_DIM + tid * 4] = o;
  if (tid == 0) rowsum[nk] = tot * inv * inv;   // ==1 unless degenerate row
}

// ---------------------------------------------------------------------------
// Kernel 3b: global L2 over flattened [K*C] per n; scale in place.
// Grid: N_B*8 = 256 blocks, 256 threads, 4096 elems/block.
// ---------------------------------------------------------------------------
__global__ __launch_bounds__(256) void k3b_globalnorm(
    const float* __restrict__ rowsum, float* __restrict__ out)
{
  const int b = blockIdx.x;
  const int n = b >> 3, seg = b & 7;
  const int tid = threadIdx.x;

  __shared__ float sg;
  float t = (tid < 64) ? rowsum[n * 64 + tid] : 0.f;
  if (tid < 64) {
#pragma unroll
    for (int off = 32; off > 0; off >>= 1) t += __shfl_xor(t, off);
    if (tid == 0) sg = t;
  }
  __syncthreads();
  float ginv = 1.f / fmaxf(sqrtf(sg), 1e-12f);

  float* ob = out + (size_t)n * (K_DIM * C_DIM) + seg * 4096;
#pragma unroll
  for (int i = 0; i < 4; ++i) {
    float4 v = *(float4*)&ob[(i * 256 + tid) * 4];
    v.x *= ginv; v.y *= ginv; v.z *= ginv; v.w *= ginv;
    *(float4*)&ob[(i * 256 + tid) * 4] = v;
  }
}

// ---------------------------------------------------------------------------
extern "C" void kernel_launch(void* const* d_in, const int* in_sizes, int n_in,
                              void* d_out, int out_size, void* d_ws, size_t ws_size,
                              hipStream_t stream) {
  (void)in_sizes; (void)n_in; (void)out_size; (void)ws_size;
  const float* x    = (const float*)d_in[0];   // [32,512,30,40]
  const float* w    = (const float*)d_in[1];   // [64,512]
  const float* cent = (const float*)d_in[2];   // [64,512]
  float* out = (float*)d_out;

  // workspace layout (bytes) — identical footprint to round-1 (known-safe)
  char* ws = (char*)d_ws;
  float* a_buf    = (float*)(ws);                                  // 9,830,400
  float* invnorm  = (float*)(ws + 9830400);                        //   153,600
  float* asum_p   = (float*)(ws + 9984000);                        //   327,680
  float* part     = (float*)(ws + 10311680);                       //16,777,216
  float* rowsum   = (float*)(ws + 27088896);                       //     8,192

  k1_logits_softmax<<<N_B * NPT, 128, 0, stream>>>(x, w, a_buf, invnorm, asum_p);
  k2_vlad_gemm<<<N_B * 32, 128, 0, stream>>>(x, a_buf, invnorm, part);
  k3a_intranorm<<<N_B * K_DIM, 128, 0, stream>>>(part, cent, asum_p, out, rowsum);
  k3b_globalnorm<<<N_B * 8, 256, 0, stream>>>(rowsum, out);
}

// Round 7
// 171.390 us; speedup vs baseline: 2.0893x; 1.7823x over previous
//
#include <hip/hip_runtime.h>
#include <hip/hip_bf16.h>
#include <math.h>

// NetVLAD, MI355X gfx950. bf16 MFMA for both GEMMs, fp32 everywhere else.
#define N_B   32
#define C_DIM 512
#define K_DIM 64
#define HW    1200
#define PTILE 32
#define NPT   38      // ceil(1200/32)
#define ASLOT 40

typedef __attribute__((ext_vector_type(8))) short bf16x8;  // 8 bf16 in 4 VGPRs
typedef __attribute__((ext_vector_type(4))) float f32x4;

static __device__ inline short f2bf(float f) {
  __hip_bfloat16 h = __float2bfloat16(f);   // RNE, single v_cvt
  union { __hip_bfloat16 b; short s; } u; u.b = h; return u.s;
}

// ---------------------------------------------------------------------------
// k1: logits = W(64x512) @ xn(512x32p) via MFMA + fused channel-sumsq +
// column softmax. Grid 32n x 38 ptiles = 1216 blocks, 256 thr (4 waves).
// Wave w computes k-rows [16w,16w+16) x 32 p. All LDS fragment accesses are
// whole aligned bf16x8 octets.
// a_out stored bf16 [n][k][h] so k2 can fragment-load it directly.
// ---------------------------------------------------------------------------
__global__ __launch_bounds__(256) void k1_logits_softmax(
    const float* __restrict__ x, const float* __restrict__ w,
    unsigned short* __restrict__ a_out, float* __restrict__ invnorm_out,
    float* __restrict__ asum_part)
{
  __shared__ bf16x8 wlds[64 * 8];   // [k][c-octet], row = 128B
  __shared__ bf16x8 xlds[32 * 8];   // [p][c-octet] (transposed during staging)
  __shared__ float  slog[64 * 36];  // [k][p] padded
  __shared__ float  sred[8 * 32];
  __shared__ float  pinv[32], pmax[32], psum[32];

  const int tid  = threadIdx.x;
  const int lane = tid & 63;
  const int wv   = tid >> 6;
  const int n    = blockIdx.x / NPT;
  const int tile = blockIdx.x % NPT;
  const int p0   = tile * PTILE;

  const int sp = tid & 31;          // staging pixel
  const int sg = tid >> 5;          // staging c-octet 0..7
  const bool spv = (p0 + sp) < HW;

  const int lr = lane & 15;         // fragment row/col index
  const int lg = lane >> 4;         // fragment k-group

  const float* xb = x + (size_t)n * C_DIM * HW;

  f32x4 acc0 = {0.f, 0.f, 0.f, 0.f};   // p-group 0
  f32x4 acc1 = {0.f, 0.f, 0.f, 0.f};   // p-group 1
  float ssq = 0.f;

  for (int c0 = 0; c0 < C_DIM; c0 += 64) {
    // stage W[0..63][c0..c0+63] -> bf16 LDS (coalesced, 16 elems/thread)
    {
      const int k = tid >> 3, o = tid & 7;
#pragma unroll
      for (int i = 0; i < 2; ++i) {
        const int kk = k + 32 * i;
        const float* wp = w + (size_t)kk * C_DIM + c0 + o * 8;
        float4 w0 = *(const float4*)wp;
        float4 w1 = *(const float4*)(wp + 4);
        bf16x8 v;
        v[0]=f2bf(w0.x); v[1]=f2bf(w0.y); v[2]=f2bf(w0.z); v[3]=f2bf(w0.w);
        v[4]=f2bf(w1.x); v[5]=f2bf(w1.y); v[6]=f2bf(w1.z); v[7]=f2bf(w1.w);
        wlds[kk * 8 + o] = v;
      }
    }
    // stage x[c0..c0+63][p0..p0+31] transposed to [p][c] bf16; fuse sumsq
    {
      float f[8];
#pragma unroll
      for (int j = 0; j < 8; ++j) {
        float v = spv ? xb[(size_t)(c0 + sg * 8 + j) * HW + p0 + sp] : 0.f;
        ssq += v * v;
        f[j] = v;
      }
      bf16x8 v;
#pragma unroll
      for (int j = 0; j < 8; ++j) v[j] = f2bf(f[j]);
      xlds[sp * 8 + sg] = v;
    }
    __syncthreads();
    // MFMA: K-chunks of 32 c (c-octets kc*4+lg)
    {
      const int kw = wv * 16;
#pragma unroll
      for (int kc = 0; kc < 2; ++kc) {
        bf16x8 af = wlds[(kw + lr) * 8 + kc * 4 + lg];
        bf16x8 b0 = xlds[lr * 8 + kc * 4 + lg];
        bf16x8 b1 = xlds[(16 + lr) * 8 + kc * 4 + lg];
        acc0 = __builtin_amdgcn_mfma_f32_16x16x32_bf16(af, b0, acc0, 0, 0, 0);
        acc1 = __builtin_amdgcn_mfma_f32_16x16x32_bf16(af, b1, acc1, 0, 0, 0);
      }
    }
    __syncthreads();
  }

  // per-pixel inv-norm
  sred[sg * 32 + sp] = ssq;
  __syncthreads();
  if (tid < 32) {
    float s = 0.f;
#pragma unroll
    for (int g = 0; g < 8; ++g) s += sred[g * 32 + tid];
    float iv = 1.f / fmaxf(sqrtf(s), 1e-12f);   // torch F.normalize eps
    pinv[tid] = iv;
    if ((p0 + tid) < HW) invnorm_out[n * HW + p0 + tid] = iv;
  }
  __syncthreads();

  // scaled logits -> slog[k][p]   (D layout: row = lg*4+r, col = lr)
  {
    const int kw = wv * 16;
    const float i0 = pinv[lr];
    const float i1 = pinv[16 + lr];
#pragma unroll
    for (int r = 0; r < 4; ++r) {
      slog[(kw + lg * 4 + r) * 36 + lr]      = acc0[r] * i0;
      slog[(kw + lg * 4 + r) * 36 + 16 + lr] = acc1[r] * i1;
    }
  }
  __syncthreads();

  // column softmax over 64 k: thread owns (p = tid&31, 8 k's)
  {
    const int p = tid & 31;
    const int kg = tid >> 5;
    float e[8];
    float m = -1e30f;
#pragma unroll
    for (int j = 0; j < 8; ++j) { e[j] = slog[(kg * 8 + j) * 36 + p]; m = fmaxf(m, e[j]); }
    sred[kg * 32 + p] = m;
    __syncthreads();
    if (tid < 32) {
      float mm = sred[tid];
#pragma unroll
      for (int g = 1; g < 8; ++g) mm = fmaxf(mm, sred[g * 32 + tid]);
      pmax[tid] = mm;
    }
    __syncthreads();
    const float M = pmax[p];
    float s = 0.f;
#pragma unroll
    for (int j = 0; j < 8; ++j) { e[j] = __expf(e[j] - M); s += e[j]; }
    sred[kg * 32 + p] = s;
    __syncthreads();
    if (tid < 32) {
      float ss = 0.f;
#pragma unroll
      for (int g = 0; g < 8; ++g) ss += sred[g * 32 + tid];
      psum[tid] = 1.f / ss;
    }
    __syncthreads();
    const float sc = psum[p];
    const bool pv = (p0 + p) < HW;
#pragma unroll
    for (int j = 0; j < 8; ++j) {
      float av = e[j] * sc;
      if (pv) a_out[((size_t)n * K_DIM + kg * 8 + j) * HW + p0 + p] =
                  (unsigned short)f2bf(av);
      float t = pv ? av : 0.f;
#pragma unroll
      for (int off = 16; off > 0; off >>= 1) t += __shfl_xor(t, off);
      if (p == 0) asum_part[((size_t)n * K_DIM + kg * 8 + j) * ASLOT + tile] = t;
    }
  }
}

// ---------------------------------------------------------------------------
// k2: vlad[k][c] = sum_h a[k][h] * xn[c][h] via MFMA, fragments straight from
// global (h is contiguous for both operands -> no LDS, no transpose).
// Grid 32n x 8ct x 2half = 512 blocks, 256 thr; wave = 16k x 64c strip.
// Writes fp32 partials part[half][n][k][c].
// ---------------------------------------------------------------------------
__global__ __launch_bounds__(256) void k2_vlad_gemm(
    const float* __restrict__ x, const unsigned short* __restrict__ a_in,
    const float* __restrict__ invnorm, float* __restrict__ part)
{
  const int tid  = threadIdx.x;
  const int lane = tid & 63;
  const int wv   = tid >> 6;
  const int b    = blockIdx.x;
  const int half = b & 1;
  const int ct   = (b >> 1) & 7;
  const int n    = b >> 4;
  const int c0   = ct * 64;
  const int hb   = half * 600;
  const int k0   = wv * 16;
  const int lr = lane & 15, lg = lane >> 4;

  const float* xb          = x       + (size_t)n * C_DIM * HW;
  const unsigned short* ab = a_in    + (size_t)n * K_DIM * HW;
  const float* inb         = invnorm + (size_t)n * HW;

  f32x4 acc[4] = {{0,0,0,0}, {0,0,0,0}, {0,0,0,0}, {0,0,0,0}};

  for (int hc = 0; hc < 600; hc += 32) {
    const int hrel = hc + lg * 8;
    const bool gv = hrel < 600;          // tail chunk: lane-group 3 invalid
    const int h = hb + hrel;

    bf16x8 af;
    float4 i0, i1;
    if (gv) {
      af = *(const bf16x8*)(ab + (size_t)(k0 + lr) * HW + h);
      i0 = *(const float4*)(inb + h);
      i1 = *(const float4*)(inb + h + 4);
    } else {
#pragma unroll
      for (int j = 0; j < 8; ++j) af[j] = 0;
      i0 = make_float4(0.f, 0.f, 0.f, 0.f);
      i1 = make_float4(0.f, 0.f, 0.f, 0.f);
    }
#pragma unroll
    for (int cg = 0; cg < 4; ++cg) {
      bf16x8 bx;
      if (gv) {
        const float* xp = xb + (size_t)(c0 + cg * 16 + lr) * HW + h;
        float4 x0 = *(const float4*)xp;
        float4 x1 = *(const float4*)(xp + 4);
        bx[0]=f2bf(x0.x*i0.x); bx[1]=f2bf(x0.y*i0.y);
        bx[2]=f2bf(x0.z*i0.z); bx[3]=f2bf(x0.w*i0.w);
        bx[4]=f2bf(x1.x*i1.x); bx[5]=f2bf(x1.y*i1.y);
        bx[6]=f2bf(x1.z*i1.z); bx[7]=f2bf(x1.w*i1.w);
      } else {
#pragma unroll
        for (int j = 0; j < 8; ++j) bx[j] = 0;
      }
      acc[cg] = __builtin_amdgcn_mfma_f32_16x16x32_bf16(af, bx, acc[cg], 0, 0, 0);
    }
  }

  float* pb = part + (((size_t)half * N_B + n) * K_DIM) * C_DIM;
#pragma unroll
  for (int cg = 0; cg < 4; ++cg)
#pragma unroll
    for (int r = 0; r < 4; ++r)
      pb[(size_t)(k0 + lg * 4 + r) * C_DIM + c0 + cg * 16 + lr] = acc[cg][r];
}

// ---------------------------------------------------------------------------
// k3a: v = part0 + part1 - asum*centroid; intra-normalize over C.
// Grid 2048 blocks, 128 threads (4 c each).
// ---------------------------------------------------------------------------
__global__ __launch_bounds__(128) void k3a_intranorm(
    const float* __restrict__ part, const float* __restrict__ cent,
    const float* __restrict__ asum_part, float* __restrict__ out,
    float* __restrict__ rowsum)
{
  const int nk = blockIdx.x;
  const int n = nk >> 6, k = nk & 63;
  const int tid = threadIdx.x;

  __shared__ float sasum;
  __shared__ float wss[2];

  float t = (tid < NPT) ? asum_part[(size_t)nk * ASLOT + tid] : 0.f;
  if (tid < 64) {
#pragma unroll
    for (int off = 32; off > 0; off >>= 1) t += __shfl_xor(t, off);
    if (tid == 0) sasum = t;
  }
  __syncthreads();
  const float asum = sasum;

  const float* p0 = part + ((size_t)n * K_DIM + k) * C_DIM;
  const float* p1 = part + ((size_t)(N_B + n) * K_DIM + k) * C_DIM;
  const float* cb = cent + (size_t)k * C_DIM;

  float4 a4 = *(const float4*)&p0[tid * 4];
  float4 b4 = *(const float4*)&p1[tid * 4];
  float4 c4 = *(const float4*)&cb[tid * 4];
  float4 v;
  v.x = a4.x + b4.x - asum * c4.x;
  v.y = a4.y + b4.y - asum * c4.y;
  v.z = a4.z + b4.z - asum * c4.z;
  v.w = a4.w + b4.w - asum * c4.w;

  float ss = v.x * v.x + v.y * v.y + v.z * v.z + v.w * v.w;
#pragma unroll
  for (int off = 32; off > 0; off >>= 1) ss += __shfl_xor(ss, off);
  if ((tid & 63) == 0) wss[tid >> 6] = ss;
  __syncthreads();
  float tot = wss[0] + wss[1];
  float inv = 1.f / fmaxf(sqrtf(tot), 1e-12f);

  float4 o = make_float4(v.x * inv, v.y * inv, v.z * inv, v.w * inv);
  *(float4*)&out[(size_t)n * (K_DIM * C_DIM) + k * C_DIM + tid * 4] = o;
  if (tid == 0) rowsum[nk] = tot * inv * inv;
}

// ---------------------------------------------------------------------------
// k3b: global L2 over [K*C] per n; scale in place. 256 blocks, 256 thr.
// ---------------------------------------------------------------------------
__global__ __launch_bounds__(256) void k3b_globalnorm(
    const float* __restrict__ rowsum, float* __restrict__ out)
{
  const int b = blockIdx.x;
  const int n = b >> 3, seg = b & 7;
  const int tid = threadIdx.x;

  __shared__ float sg;
  float t = (tid < 64) ? rowsum[n * 64 + tid] : 0.f;
  if (tid < 64) {
#pragma unroll
    for (int off = 32; off > 0; off >>= 1) t += __shfl_xor(t, off);
    if (tid == 0) sg = t;
  }
  __syncthreads();
  float ginv = 1.f / fmaxf(sqrtf(sg), 1e-12f);

  float* ob = out + (size_t)n * (K_DIM * C_DIM) + seg * 4096;
#pragma unroll
  for (int i = 0; i < 4; ++i) {
    float4 v = *(float4*)&ob[(i * 256 + tid) * 4];
    v.x *= ginv; v.y *= ginv; v.z *= ginv; v.w *= ginv;
    *(float4*)&ob[(i * 256 + tid) * 4] = v;
  }
}

// ---------------------------------------------------------------------------
extern "C" void kernel_launch(void* const* d_in, const int* in_sizes, int n_in,
                              void* d_out, int out_size, void* d_ws, size_t ws_size,
                              hipStream_t stream) {
  (void)in_sizes; (void)n_in; (void)out_size; (void)ws_size;
  const float* x    = (const float*)d_in[0];   // [32,512,30,40]
  const float* w    = (const float*)d_in[1];   // [64,512]
  const float* cent = (const float*)d_in[2];   // [64,512]
  float* out = (float*)d_out;

  // workspace layout (bytes), all 16B-aligned
  char* ws = (char*)d_ws;
  unsigned short* a_buf = (unsigned short*)(ws);        //  4,915,200 (bf16 a)
  float* invnorm  = (float*)(ws + 4915200);             //    153,600
  float* asum_p   = (float*)(ws + 5068800);             //    327,680
  float* part     = (float*)(ws + 5396480);             // 16,777,216
  float* rowsum   = (float*)(ws + 22173696);            //      8,192

  k1_logits_softmax<<<N_B * NPT, 256, 0, stream>>>(x, w, a_buf, invnorm, asum_p);
  k2_vlad_gemm<<<N_B * 16, 256, 0, stream>>>(x, a_buf, invnorm, part);
  k3a_intranorm<<<N_B * K_DIM, 128, 0, stream>>>(part, cent, asum_p, out, rowsum);
  k3b_globalnorm<<<N_B * 8, 256, 0, stream>>>(rowsum, out);
}

// Round 11
// 167.519 us; speedup vs baseline: 2.1376x; 1.0231x over previous
//
#include <hip/hip_runtime.h>
#include <hip/hip_bf16.h>
#include <math.h>

// NetVLAD, MI355X gfx950. bf16 MFMA for both GEMMs, fp32 everywhere else.
// R8: k2 parallelism 2x (1024 blocks, 32c-tiles), invnorm folded into a.
#define N_B   32
#define C_DIM 512
#define K_DIM 64
#define HW    1200
#define PTILE 32
#define NPT   38      // ceil(1200/32)
#define ASLOT 40

typedef __attribute__((ext_vector_type(8))) short bf16x8;  // 8 bf16 in 4 VGPRs
typedef __attribute__((ext_vector_type(4))) float f32x4;

static __device__ inline short f2bf(float f) {
  __hip_bfloat16 h = __float2bfloat16(f);   // RNE, single v_cvt
  union { __hip_bfloat16 b; short s; } u; u.b = h; return u.s;
}

// ---------------------------------------------------------------------------
// k1: logits = W(64x512) @ xn(512x32p) via MFMA + fused channel-sumsq +
// column softmax. Grid 32n x 38 ptiles = 1216 blocks, 256 thr (4 waves).
// Stores a_scaled[n][k][h] = softmax_a * invnorm (bf16) so k2 needs no
// invnorm pass: sum_h a*(x*inv) == sum_h (a*inv)*x.
// ---------------------------------------------------------------------------
__global__ __launch_bounds__(256) void k1_logits_softmax(
    const float* __restrict__ x, const float* __restrict__ w,
    unsigned short* __restrict__ a_out, float* __restrict__ asum_part)
{
  __shared__ bf16x8 wlds[64 * 8];   // [k][c-octet], row = 128B
  __shared__ bf16x8 xlds[32 * 8];   // [p][c-octet] (transposed during staging)
  __shared__ float  slog[64 * 36];  // [k][p] padded
  __shared__ float  sred[8 * 32];
  __shared__ float  pinv[32], pmax[32], psum[32];

  const int tid  = threadIdx.x;
  const int lane = tid & 63;
  const int wv   = tid >> 6;
  const int n    = blockIdx.x / NPT;
  const int tile = blockIdx.x % NPT;
  const int p0   = tile * PTILE;

  const int sp = tid & 31;          // staging pixel
  const int sg = tid >> 5;          // staging c-octet 0..7
  const bool spv = (p0 + sp) < HW;

  const int lr = lane & 15;         // fragment row/col index
  const int lg = lane >> 4;         // fragment k-group

  const float* xb = x + (size_t)n * C_DIM * HW;

  f32x4 acc0 = {0.f, 0.f, 0.f, 0.f};   // p-group 0
  f32x4 acc1 = {0.f, 0.f, 0.f, 0.f};   // p-group 1
  float ssq = 0.f;

  for (int c0 = 0; c0 < C_DIM; c0 += 64) {
    // stage W[0..63][c0..c0+63] -> bf16 LDS (coalesced, 16 elems/thread)
    {
      const int k = tid >> 3, o = tid & 7;
#pragma unroll
      for (int i = 0; i < 2; ++i) {
        const int kk = k + 32 * i;
        const float* wp = w + (size_t)kk * C_DIM + c0 + o * 8;
        float4 w0 = *(const float4*)wp;
        float4 w1 = *(const float4*)(wp + 4);
        bf16x8 v;
        v[0]=f2bf(w0.x); v[1]=f2bf(w0.y); v[2]=f2bf(w0.z); v[3]=f2bf(w0.w);
        v[4]=f2bf(w1.x); v[5]=f2bf(w1.y); v[6]=f2bf(w1.z); v[7]=f2bf(w1.w);
        wlds[kk * 8 + o] = v;
      }
    }
    // stage x[c0..c0+63][p0..p0+31] transposed to [p][c] bf16; fuse sumsq
    {
      float f[8];
#pragma unroll
      for (int j = 0; j < 8; ++j) {
        float v = spv ? xb[(size_t)(c0 + sg * 8 + j) * HW + p0 + sp] : 0.f;
        ssq += v * v;
        f[j] = v;
      }
      bf16x8 v;
#pragma unroll
      for (int j = 0; j < 8; ++j) v[j] = f2bf(f[j]);
      xlds[sp * 8 + sg] = v;
    }
    __syncthreads();
    // MFMA: K-chunks of 32 c (c-octets kc*4+lg)
    {
      const int kw = wv * 16;
#pragma unroll
      for (int kc = 0; kc < 2; ++kc) {
        bf16x8 af = wlds[(kw + lr) * 8 + kc * 4 + lg];
        bf16x8 b0 = xlds[lr * 8 + kc * 4 + lg];
        bf16x8 b1 = xlds[(16 + lr) * 8 + kc * 4 + lg];
        acc0 = __builtin_amdgcn_mfma_f32_16x16x32_bf16(af, b0, acc0, 0, 0, 0);
        acc1 = __builtin_amdgcn_mfma_f32_16x16x32_bf16(af, b1, acc1, 0, 0, 0);
      }
    }
    __syncthreads();
  }

  // per-pixel inv-norm
  sred[sg * 32 + sp] = ssq;
  __syncthreads();
  if (tid < 32) {
    float s = 0.f;
#pragma unroll
    for (int g = 0; g < 8; ++g) s += sred[g * 32 + tid];
    pinv[tid] = 1.f / fmaxf(sqrtf(s), 1e-12f);   // torch F.normalize eps
  }
  __syncthreads();

  // scaled logits -> slog[k][p]   (D layout: row = lg*4+r, col = lr)
  {
    const int kw = wv * 16;
    const float i0 = pinv[lr];
    const float i1 = pinv[16 + lr];
#pragma unroll
    for (int r = 0; r < 4; ++r) {
      slog[(kw + lg * 4 + r) * 36 + lr]      = acc0[r] * i0;
      slog[(kw + lg * 4 + r) * 36 + 16 + lr] = acc1[r] * i1;
    }
  }
  __syncthreads();

  // column softmax over 64 k: thread owns (p = tid&31, 8 k's)
  {
    const int p = tid & 31;
    const int kg = tid >> 5;
    float e[8];
    float m = -1e30f;
#pragma unroll
    for (int j = 0; j < 8; ++j) { e[j] = slog[(kg * 8 + j) * 36 + p]; m = fmaxf(m, e[j]); }
    sred[kg * 32 + p] = m;
    __syncthreads();
    if (tid < 32) {
      float mm = sred[tid];
#pragma unroll
      for (int g = 1; g < 8; ++g) mm = fmaxf(mm, sred[g * 32 + tid]);
      pmax[tid] = mm;
    }
    __syncthreads();
    const float M = pmax[p];
    float s = 0.f;
#pragma unroll
    for (int j = 0; j < 8; ++j) { e[j] = __expf(e[j] - M); s += e[j]; }
    sred[kg * 32 + p] = s;
    __syncthreads();
    if (tid < 32) {
      float ss = 0.f;
#pragma unroll
      for (int g = 0; g < 8; ++g) ss += sred[g * 32 + tid];
      psum[tid] = 1.f / ss;
    }
    __syncthreads();
    const float sc = psum[p];
    const float iv = pinv[p];
    const bool pv = (p0 + p) < HW;
#pragma unroll
    for (int j = 0; j < 8; ++j) {
      float av = e[j] * sc;                 // true softmax value (for asum)
      float t = pv ? av : 0.f;
#pragma unroll
      for (int off = 16; off > 0; off >>= 1) t += __shfl_xor(t, off);
      if (p == 0) asum_part[((size_t)n * K_DIM + kg * 8 + j) * ASLOT + tile] = t;
      if (pv) a_out[((size_t)n * K_DIM + kg * 8 + j) * HW + p0 + p] =
                  (unsigned short)f2bf(av * iv);   // a*inv folded for k2
    }
  }
}

// ---------------------------------------------------------------------------
// k2: vlad[k][c] = sum_h a_scaled[k][h] * x[c][h] via MFMA, fragments straight
// from global (h contiguous for both operands -> no LDS).
// Grid 32n * 16ct * 2half = 1024 blocks, 256 thr; wave = 16k x 32c strip.
// 4 waves/SIMD chip-wide for latency hiding. Writes part[half][n][k][c].
// ---------------------------------------------------------------------------
__global__ __launch_bounds__(256) void k2_vlad_gemm(
    const float* __restrict__ x, const unsigned short* __restrict__ a_in,
    float* __restrict__ part)
{
  const int tid  = threadIdx.x;
  const int lane = tid & 63;
  const int wv   = tid >> 6;
  const int b    = blockIdx.x;
  const int half = b & 1;
  const int ct   = (b >> 1) & 15;
  const int n    = b >> 5;
  const int c0   = ct * 32;
  const int hb   = half * 600;
  const int k0   = wv * 16;
  const int lr = lane & 15, lg = lane >> 4;

  const float* xb          = x    + (size_t)n * C_DIM * HW;
  const unsigned short* ab = a_in + (size_t)n * K_DIM * HW;

  f32x4 acc0 = {0,0,0,0}, acc1 = {0,0,0,0};

#pragma unroll 2
  for (int hc = 0; hc < 600; hc += 32) {
    const int hrel = hc + lg * 8;
    const bool gv = hrel < 600;          // tail chunk: lane-group 3 invalid
    const int h = hb + hrel;

    bf16x8 af;
    bf16x8 bx0, bx1;
    if (gv) {
      af = *(const bf16x8*)(ab + (size_t)(k0 + lr) * HW + h);
      {
        const float* xp = xb + (size_t)(c0 + lr) * HW + h;
        float4 x0 = *(const float4*)xp;
        float4 x1 = *(const float4*)(xp + 4);
        bx0[0]=f2bf(x0.x); bx0[1]=f2bf(x0.y); bx0[2]=f2bf(x0.z); bx0[3]=f2bf(x0.w);
        bx0[4]=f2bf(x1.x); bx0[5]=f2bf(x1.y); bx0[6]=f2bf(x1.z); bx0[7]=f2bf(x1.w);
      }
      {
        const float* xp = xb + (size_t)(c0 + 16 + lr) * HW + h;
        float4 x0 = *(const float4*)xp;
        float4 x1 = *(const float4*)(xp + 4);
        bx1[0]=f2bf(x0.x); bx1[1]=f2bf(x0.y); bx1[2]=f2bf(x0.z); bx1[3]=f2bf(x0.w);
        bx1[4]=f2bf(x1.x); bx1[5]=f2bf(x1.y); bx1[6]=f2bf(x1.z); bx1[7]=f2bf(x1.w);
      }
    } else {
#pragma unroll
      for (int j = 0; j < 8; ++j) { af[j] = 0; bx0[j] = 0; bx1[j] = 0; }
    }
    acc0 = __builtin_amdgcn_mfma_f32_16x16x32_bf16(af, bx0, acc0, 0, 0, 0);
    acc1 = __builtin_amdgcn_mfma_f32_16x16x32_bf16(af, bx1, acc1, 0, 0, 0);
  }

  float* pb = part + (((size_t)half * N_B + n) * K_DIM) * C_DIM;
#pragma unroll
  for (int r = 0; r < 4; ++r) {
    pb[(size_t)(k0 + lg * 4 + r) * C_DIM + c0 + lr]      = acc0[r];
    pb[(size_t)(k0 + lg * 4 + r) * C_DIM + c0 + 16 + lr] = acc1[r];
  }
}

// ---------------------------------------------------------------------------
// k3a: v = part0 + part1 - asum*centroid; intra-normalize over C.
// Grid 2048 blocks, 128 threads (4 c each).
// ---------------------------------------------------------------------------
__global__ __launch_bounds__(128) void k3a_intranorm(
    const float* __restrict__ part, const float* __restrict__ cent,
    const float* __restrict__ asum_part, float* __restrict__ out,
    float* __restrict__ rowsum)
{
  const int nk = blockIdx.x;
  const int n = nk >> 6, k = nk & 63;
  const int tid = threadIdx.x;

  __shared__ float sasum;
  __shared__ float wss[2];

  float t = (tid < NPT) ? asum_part[(size_t)nk * ASLOT + tid] : 0.f;
  if (tid < 64) {
#pragma unroll
    for (int off = 32; off > 0; off >>= 1) t += __shfl_xor(t, off);
    if (tid == 0) sasum = t;
  }
  __syncthreads();
  const float asum = sasum;

  const float* p0 = part + ((size_t)n * K_DIM + k) * C_DIM;
  const float* p1 = part + ((size_t)(N_B + n) * K_DIM + k) * C_DIM;
  const float* cb = cent + (size_t)k * C_DIM;

  float4 a4 = *(const float4*)&p0[tid * 4];
  float4 b4 = *(const float4*)&p1[tid * 4];
  float4 c4 = *(const float4*)&cb[tid * 4];
  float4 v;
  v.x = a4.x + b4.x - asum * c4.x;
  v.y = a4.y + b4.y - asum * c4.y;
  v.z = a4.z + b4.z - asum * c4.z;
  v.w = a4.w + b4.w - asum * c4.w;

  float ss = v.x * v.x + v.y * v.y + v.z * v.z + v.w * v.w;
#pragma unroll
  for (int off = 32; off > 0; off >>= 1) ss += __shfl_xor(ss, off);
  if ((tid & 63) == 0) wss[tid >> 6] = ss;
  __syncthreads();
  float tot = wss[0] + wss[1];
  float inv = 1.f / fmaxf(sqrtf(tot), 1e-12f);

  float4 o = make_float4(v.x * inv, v.y * inv, v.z * inv, v.w * inv);
  *(float4*)&out[(size_t)n * (K_DIM * C_DIM) + k * C_DIM + tid * 4] = o;
  if (tid == 0) rowsum[nk] = tot * inv * inv;
}

// ---------------------------------------------------------------------------
// k3b: global L2 over [K*C] per n; scale in place. 256 blocks, 256 thr.
// ---------------------------------------------------------------------------
__global__ __launch_bounds__(256) void k3b_globalnorm(
    const float* __restrict__ rowsum, float* __restrict__ out)
{
  const int b = blockIdx.x;
  const int n = b >> 3, seg = b & 7;
  const int tid = threadIdx.x;

  __shared__ float sg;
  float t = (tid < 64) ? rowsum[n * 64 + tid] : 0.f;
  if (tid < 64) {
#pragma unroll
    for (int off = 32; off > 0; off >>= 1) t += __shfl_xor(t, off);
    if (tid == 0) sg = t;
  }
  __syncthreads();
  float ginv = 1.f / fmaxf(sqrtf(sg), 1e-12f);

  float* ob = out + (size_t)n * (K_DIM * C_DIM) + seg * 4096;
#pragma unroll
  for (int i = 0; i < 4; ++i) {
    float4 v = *(float4*)&ob[(i * 256 + tid) * 4];
    v.x *= ginv; v.y *= ginv; v.z *= ginv; v.w *= ginv;
    *(float4*)&ob[(i * 256 + tid) * 4] = v;
  }
}

// ---------------------------------------------------------------------------
extern "C" void kernel_launch(void* const* d_in, const int* in_sizes, int n_in,
                              void* d_out, int out_size, void* d_ws, size_t ws_size,
                              hipStream_t stream) {
  (void)in_sizes; (void)n_in; (void)out_size; (void)ws_size;
  const float* x    = (const float*)d_in[0];   // [32,512,30,40]
  const float* w    = (const float*)d_in[1];   // [64,512]
  const float* cent = (const float*)d_in[2];   // [64,512]
  float* out = (float*)d_out;

  // workspace layout (bytes), all 16B-aligned
  char* ws = (char*)d_ws;
  unsigned short* a_buf = (unsigned short*)(ws);        //  4,915,200 (bf16 a*inv)
  float* asum_p   = (float*)(ws + 4915200);             //    327,680
  float* part     = (float*)(ws + 5242880);             // 16,777,216
  float* rowsum   = (float*)(ws + 22020096);            //      8,192

  k1_logits_softmax<<<N_B * NPT, 256, 0, stream>>>(x, w, a_buf, asum_p);
  k2_vlad_gemm<<<N_B * 32, 256, 0, stream>>>(x, a_buf, part);
  k3a_intranorm<<<N_B * K_DIM, 128, 0, stream>>>(part, cent, asum_p, out, rowsum);
  k3b_globalnorm<<<N_B * 8, 256, 0, stream>>>(rowsum, out);
}